// Round 3
// baseline (3065.003 us; speedup 1.0000x reference)
//
#include <hip/hip_runtime.h>
#include <hip/hip_bf16.h>

#define N_EXP   8
#define NTOK    2048   // B*S
#define TOTROWS 4096   // NTOK * TOP_K
#define CH      1024   // chunk rows for the inner F->2F->F pair

typedef __hip_bfloat16 bf16;

// ---------------- helpers ----------------

__device__ inline float gelu_f(float v) {
    return 0.5f * v * (1.0f + erff(v * 0.70710678118654752440f));
}

__device__ inline float block_sum256(float v, float* red) {
    #pragma unroll
    for (int off = 32; off > 0; off >>= 1)
        v += __shfl_down(v, off, 64);
    __syncthreads();
    if ((threadIdx.x & 63) == 0) red[threadIdx.x >> 6] = v;
    __syncthreads();
    return red[0] + red[1] + red[2] + red[3];
}

__device__ inline unsigned rotl32(unsigned v, int d) { return (v << d) | (v >> (32 - d)); }

// JAX threefry2x32, key = (k0,k1), 20 rounds
__device__ inline void threefry2x32(unsigned k0, unsigned k1, unsigned x0, unsigned x1,
                                    unsigned& o0, unsigned& o1) {
    unsigned ks2 = k0 ^ k1 ^ 0x1BD11BDAu;
    x0 += k0; x1 += k1;
#define TF_R(r) { x0 += x1; x1 = rotl32(x1, r); x1 ^= x0; }
    TF_R(13) TF_R(15) TF_R(26) TF_R(6)
    x0 += k1; x1 += ks2 + 1u;
    TF_R(17) TF_R(29) TF_R(16) TF_R(24)
    x0 += ks2; x1 += k0 + 2u;
    TF_R(13) TF_R(15) TF_R(26) TF_R(6)
    x0 += k0; x1 += k1 + 3u;
    TF_R(17) TF_R(29) TF_R(16) TF_R(24)
    x0 += k1; x1 += ks2 + 4u;
    TF_R(13) TF_R(15) TF_R(26) TF_R(6)
    x0 += ks2; x1 += k0 + 5u;
#undef TF_R
    o0 = x0; o1 = x1;
}

__device__ inline int expert_of(int r, const int* bases) {
    int e = 0;
    #pragma unroll
    for (int i = 1; i < N_EXP; ++i) if (r >= bases[i]) e = i;
    return e;
}

// ---------------- policy + routing ----------------

__global__ __launch_bounds__(256) void policy_k(
    const float* __restrict__ x, const float* __restrict__ pw1,
    const float* __restrict__ pb1, const float* __restrict__ pg1,
    const float* __restrict__ pbb1, const float* __restrict__ pw2,
    const float* __restrict__ pb2, int2* __restrict__ top2, int* __restrict__ counts)
{
    const int t = blockIdx.x;
    const int lid = threadIdx.x;
    __shared__ float xs[512];
    __shared__ float hb[256];
    __shared__ float red[4];
    __shared__ float sc[8];

    xs[lid]       = x[(long long)t * 512 + lid];
    xs[lid + 256] = x[(long long)t * 512 + 256 + lid];
    __syncthreads();

    float acc = pb1[lid];
    for (int d = 0; d < 512; ++d)
        acc = fmaf(xs[d], pw1[d * 256 + lid], acc);

    float s  = block_sum256(acc, red);
    float sq = block_sum256(acc * acc, red);
    float mean = s * (1.0f / 256.0f);
    float var  = sq * (1.0f / 256.0f) - mean * mean;
    float rstd = rsqrtf(var + 1e-5f);
    float hn = (acc - mean) * rstd * pg1[lid] + pbb1[lid];
    hb[lid] = gelu_f(hn);
    __syncthreads();

    if (lid < 8) {
        float lg = pb2[lid];
        for (int j = 0; j < 256; ++j)
            lg = fmaf(hb[j], pw2[j * 8 + lid], lg);
        // Gumbel noise matching jax.random.uniform(key(42), [B,S,E]) under
        // jax_threefry_partitionable=True (default since JAX 0.4.30):
        // per element i: threefry2x32(key, hi32(i)=0, lo32(i)=i), bits = o0 ^ o1.
        unsigned idx = (unsigned)t * 8u + (unsigned)lid;
        unsigned o0, o1;
        threefry2x32(0u, 42u, 0u, idx, o0, o1);
        unsigned bits = o0 ^ o1;
        float u = __uint_as_float((bits >> 9) | 0x3f800000u) - 1.0f;
        float gml = -logf(-logf(u + 1e-10f) + 1e-10f);
        sc[lid] = lg + gml;   // TEMP = 1
    }
    __syncthreads();
    if (lid == 0) {
        float b0 = -INFINITY; int i0 = 0;
        #pragma unroll
        for (int e = 0; e < 8; ++e) if (sc[e] > b0) { b0 = sc[e]; i0 = e; }
        float b1v = -INFINITY; int i1 = 0;
        #pragma unroll
        for (int e = 0; e < 8; ++e) if (e != i0 && sc[e] > b1v) { b1v = sc[e]; i1 = e; }
        top2[t] = make_int2(i0, i1);
        atomicAdd(&counts[i0], 1);
        atomicAdd(&counts[i1], 1);
    }
}

__global__ void prefix_k(const int* __restrict__ counts, int* __restrict__ cursor,
                         int* __restrict__ bases) {
    if (threadIdx.x == 0 && blockIdx.x == 0) {
        int s = 0;
        for (int e = 0; e < N_EXP; ++e) { bases[e] = s; cursor[e] = s; s += counts[e]; }
    }
}

__global__ __launch_bounds__(256) void scatter_k(const int2* __restrict__ top2,
                                                 int* __restrict__ cursor,
                                                 int* __restrict__ list) {
    int t = blockIdx.x * 256 + threadIdx.x;
    int2 p = top2[t];
    int pos = atomicAdd(&cursor[p.x], 1); list[pos] = t;
    pos     = atomicAdd(&cursor[p.y], 1); list[pos] = t;
}

// ---------------- grouped GEMM (fp32 acc, 64x64x16 tile, 4x4/thread) ----------------
// Row space: global compact rows [row_lo, row_hi). a_local/c_local: index A/C rows
// relative to row_lo (chunk buffers). gather: physical A row = list[r] (x rows).

template <typename AT, typename CT>
__global__ __launch_bounds__(256) void gemm_k(
    const AT* __restrict__ A, const int* __restrict__ gather,
    const float* __restrict__ W, long long westride,
    const float* __restrict__ bias, int bestride,
    CT* __restrict__ C,
    const int* __restrict__ counts, const int* __restrict__ bases,
    int row_lo, int row_hi, int K, int N, int act, int a_local, int c_local)
{
    const int e = blockIdx.z;
    const int gstart = bases[e];
    const int gend = gstart + counts[e];
    const int lo = max(gstart, row_lo);
    const int hi = min(gend, row_hi);
    if (lo >= hi) return;
    const int m0 = lo + blockIdx.y * 64;
    if (m0 >= hi) return;
    const int n0 = blockIdx.x * 64;
    const float* We = W + (long long)e * westride;

    __shared__ float As[16][64 + 4];
    __shared__ float Bs[16][64 + 4];

    const int lid = threadIdx.x;
    const int tx = lid & 15, ty = lid >> 4;
    const int ka = lid & 15, ma = lid >> 4;   // A-load: k, row-group
    const int nb_ = lid & 63, kb = lid >> 6;  // B-load: n, k-group

    long long arow[4];
    #pragma unroll
    for (int i = 0; i < 4; ++i) {
        int r = m0 + ma + 16 * i;
        if (r > hi - 1) r = hi - 1;
        long long pr = gather ? (long long)gather[r]
                              : (long long)(a_local ? r - row_lo : r);
        arow[i] = pr * (long long)K;
    }

    float acc[4][4] = {};

    for (int k0 = 0; k0 < K; k0 += 16) {
        #pragma unroll
        for (int i = 0; i < 4; ++i)
            As[ka][ma + 16 * i] = (float)A[arow[i] + k0 + ka];
        #pragma unroll
        for (int i = 0; i < 4; ++i) {
            int k = kb + 4 * i;
            Bs[k][nb_] = We[(long long)(k0 + k) * N + n0 + nb_];
        }
        __syncthreads();
        #pragma unroll
        for (int kk = 0; kk < 16; ++kk) {
            float a[4], b[4];
            #pragma unroll
            for (int i = 0; i < 4; ++i) a[i] = As[kk][ty * 4 + i];
            #pragma unroll
            for (int j = 0; j < 4; ++j) b[j] = Bs[kk][tx * 4 + j];
            #pragma unroll
            for (int i = 0; i < 4; ++i)
                #pragma unroll
                for (int j = 0; j < 4; ++j)
                    acc[i][j] = fmaf(a[i], b[j], acc[i][j]);
        }
        __syncthreads();
    }

    #pragma unroll
    for (int i = 0; i < 4; ++i) {
        int r = m0 + ty * 4 + i;
        if (r >= hi) continue;
        long long crow = (long long)(c_local ? r - row_lo : r) * N;
        #pragma unroll
        for (int j = 0; j < 4; ++j) {
            int n = n0 + tx * 4 + j;
            float v = acc[i][j] + bias[e * bestride + n];
            if (act == 1) v = gelu_f(v);
            C[crow + n] = (CT)v;
        }
    }
}

// ---------------- LN + gate + residual (per row, F=1024); h2 is chunk-local ----------------

__global__ __launch_bounds__(256) void lngate_k(
    float* __restrict__ h, const float* __restrict__ h2,
    const float* __restrict__ ng, const float* __restrict__ nb,
    const float* __restrict__ gw, const int* __restrict__ bases,
    int row_lo, int l)
{
    const int r = row_lo + blockIdx.x;           // global compact row (always valid)
    const int e = expert_of(r, bases);
    const int lid = threadIdx.x;
    const float* hr  = h  + (long long)r * 1024;
    const float* h2r = h2 + (long long)(r - row_lo) * 1024;
    const int off = (e * 2 + l) * 1024;
    __shared__ float red[4];

    float s = 0.f, sq = 0.f, dt = 0.f;
    float hv[4], h2v[4];
    #pragma unroll
    for (int i = 0; i < 4; ++i) {
        int j = lid + 256 * i;
        float a = h2r[j];
        float b = hr[j];
        hv[i] = b; h2v[i] = a;
        s += a; sq += a * a;
        dt = fmaf(b, gw[off + j], dt);
    }
    s  = block_sum256(s, red);
    sq = block_sum256(sq, red);
    dt = block_sum256(dt, red);
    float mean = s * (1.f / 1024.f);
    float rstd = rsqrtf(sq * (1.f / 1024.f) - mean * mean + 1e-5f);
    float gate = 1.f / (1.f + expf(-dt));
    float* hw = h + (long long)r * 1024;
    #pragma unroll
    for (int i = 0; i < 4; ++i) {
        int j = lid + 256 * i;
        float v = (h2v[i] - mean) * rstd * ng[off + j] + nb[off + j];
        hw[j] = hv[i] + gate * v;
    }
}

// ---------------- final LN(x + out) + combine ----------------

__global__ __launch_bounds__(256) void final_k(
    const float* __restrict__ x, const bf16* __restrict__ orow,
    const float* __restrict__ fng, const float* __restrict__ fnb,
    const int* __restrict__ bases, const int* __restrict__ list,
    float* __restrict__ out)
{
    const int r = blockIdx.x;                    // global compact row, [0,4096)
    const int e = expert_of(r, bases);
    const int t = list[r];
    const int lid = threadIdx.x;
    __shared__ float red[4];

    float y[2];
    float s = 0.f, sq = 0.f;
    #pragma unroll
    for (int i = 0; i < 2; ++i) {
        int j = lid + 256 * i;
        float v = x[(long long)t * 512 + j] + (float)orow[(long long)r * 512 + j];
        y[i] = v; s += v; sq += v * v;
    }
    s  = block_sum256(s, red);
    sq = block_sum256(sq, red);
    float mean = s * (1.f / 512.f);
    float rstd = rsqrtf(sq * (1.f / 512.f) - mean * mean + 1e-5f);
    #pragma unroll
    for (int i = 0; i < 2; ++i) {
        int j = lid + 256 * i;
        float v = (y[i] - mean) * rstd * fng[e * 512 + j] + fnb[e * 512 + j];
        atomicAdd(&out[(long long)t * 512 + j], v);
    }
}

// ---------------- launch ----------------

extern "C" void kernel_launch(void* const* d_in, const int* in_sizes, int n_in,
                              void* d_out, int out_size, void* d_ws, size_t ws_size,
                              hipStream_t stream) {
    const float* x    = (const float*)d_in[0];
    const float* pw1  = (const float*)d_in[1];
    const float* pb1  = (const float*)d_in[2];
    const float* pg1  = (const float*)d_in[3];
    const float* pbb1 = (const float*)d_in[4];
    const float* pw2  = (const float*)d_in[5];
    const float* pb2  = (const float*)d_in[6];
    const float* Win  = (const float*)d_in[7];
    const float* b_in = (const float*)d_in[8];
    const float* W1   = (const float*)d_in[9];
    const float* b1   = (const float*)d_in[10];
    const float* W2   = (const float*)d_in[11];
    const float* b2   = (const float*)d_in[12];
    const float* ng   = (const float*)d_in[13];
    const float* nb   = (const float*)d_in[14];
    const float* gw   = (const float*)d_in[15];
    const float* Wout = (const float*)d_in[16];
    const float* bout = (const float*)d_in[17];
    const float* fng  = (const float*)d_in[18];
    const float* fnb  = (const float*)d_in[19];
    float* out = (float*)d_out;
    (void)ws_size; (void)in_sizes; (void)n_in;

    char* ws = (char*)d_ws;
    int* counts = (int*)ws;        // 8 ints @ 0
    int* cursor = counts + 8;      // 8 ints @ 32
    int* bases  = cursor + 8;      // 8 ints @ 64
    int2* top2  = (int2*)(ws + 128);             // 2048 * 8B = 16 KB
    int*  list  = (int*)(ws + 128 + 2048 * 8);   // 4096 * 4B = 16 KB
    size_t o = 128 + 2048 * 8 + 4096 * 4;
    o = (o + 255) & ~(size_t)255;
    float* h    = (float*)(ws + o); o += (size_t)TOTROWS * 1024 * 4;  // 16 MB
    bf16*  tb   = (bf16*) (ws + o); o += (size_t)CH * 2048 * 2;       //  4 MB
    float* h2   = (float*)(ws + o); o += (size_t)CH * 1024 * 4;       //  4 MB
    bf16*  orow = (bf16*) (ws + o); o += (size_t)TOTROWS * 512 * 2;   //  4 MB
    // total ~28.05 MB

    hipMemsetAsync(d_out, 0, (size_t)out_size * sizeof(float), stream);
    hipMemsetAsync(ws, 0, 64, stream);  // counts + cursor

    policy_k<<<NTOK, 256, 0, stream>>>(x, pw1, pb1, pg1, pbb1, pw2, pb2, top2, counts);
    prefix_k<<<1, 64, 0, stream>>>(counts, cursor, bases);
    scatter_k<<<NTOK / 256, 256, 0, stream>>>(top2, cursor, list);

    // h = gather(x) @ Win_e + b_in        [4096,512]x[512,1024]
    gemm_k<float, float><<<dim3(16, 32, 8), 256, 0, stream>>>(
        x, list, Win, (long long)512 * 1024, b_in, 1024, h,
        counts, bases, 0, TOTROWS, 512, 1024, 0, 0, 0);

    for (int l = 0; l < 2; ++l) {
        for (int c = 0; c < TOTROWS / CH; ++c) {
            int rlo = c * CH, rhi = rlo + CH;
            // tb = gelu(h @ W1_el + b1)   [CH,1024]x[1024,2048] -> bf16 local
            gemm_k<float, bf16><<<dim3(32, CH / 64, 8), 256, 0, stream>>>(
                h, nullptr, W1 + (long long)l * 1024 * 2048, (long long)2 * 1024 * 2048,
                b1 + l * 2048, 2 * 2048, tb,
                counts, bases, rlo, rhi, 1024, 2048, 1, 0, 1);
            // h2 = tb @ W2_el + b2        [CH,2048]x[2048,1024] -> f32 local
            gemm_k<bf16, float><<<dim3(16, CH / 64, 8), 256, 0, stream>>>(
                tb, nullptr, W2 + (long long)l * 2048 * 1024, (long long)2 * 2048 * 1024,
                b2 + l * 1024, 2 * 1024, h2,
                counts, bases, rlo, rhi, 2048, 1024, 0, 1, 1);
            // h += sigmoid(h . gw) * LN(h2)
            lngate_k<<<dim3(CH), 256, 0, stream>>>(h, h2, ng, nb, gw, bases, rlo, l);
        }
    }

    // orow = h @ Wout_e + bout            [4096,1024]x[1024,512] -> bf16 global
    gemm_k<float, bf16><<<dim3(8, 32, 8), 256, 0, stream>>>(
        h, nullptr, Wout, (long long)1024 * 512, bout, 512, orow,
        counts, bases, 0, TOTROWS, 1024, 512, 0, 0, 0);

    // out[t] += LN(x[t] + orow)
    final_k<<<dim3(TOTROWS), 256, 0, stream>>>(x, orow, fng, fnb, bases, list, out);
}

// Round 4
// 1269.571 us; speedup vs baseline: 2.4142x; 2.4142x over previous
//
#include <hip/hip_runtime.h>
#include <hip/hip_bf16.h>

#define N_EXP   8
#define NTOK    2048   // B*S
#define TOTROWS 4096   // NTOK * TOP_K

typedef __hip_bfloat16 bf16;
typedef __attribute__((ext_vector_type(8))) short short8;   // 8 bf16 (4 VGPRs)
typedef __attribute__((ext_vector_type(4))) float floatx4;  // MFMA acc

#define TM 128
#define TN 128
#define TK 32
#define LDAB 40   // padded bf16 row stride for LDS tiles (80B: 16B-aligned, 2-way max)

// ---------------- helpers ----------------

__device__ inline float gelu_f(float v) {
    return 0.5f * v * (1.0f + erff(v * 0.70710678118654752440f));
}

__device__ inline float block_sum256(float v, float* red) {
    #pragma unroll
    for (int off = 32; off > 0; off >>= 1)
        v += __shfl_down(v, off, 64);
    __syncthreads();
    if ((threadIdx.x & 63) == 0) red[threadIdx.x >> 6] = v;
    __syncthreads();
    return red[0] + red[1] + red[2] + red[3];
}

__device__ inline unsigned rotl32(unsigned v, int d) { return (v << d) | (v >> (32 - d)); }

// JAX threefry2x32, key = (k0,k1)
__device__ inline void threefry2x32(unsigned k0, unsigned k1, unsigned x0, unsigned x1,
                                    unsigned& o0, unsigned& o1) {
    unsigned ks2 = k0 ^ k1 ^ 0x1BD11BDAu;
    x0 += k0; x1 += k1;
#define TF_R(r) { x0 += x1; x1 = rotl32(x1, r); x1 ^= x0; }
    TF_R(13) TF_R(15) TF_R(26) TF_R(6)
    x0 += k1; x1 += ks2 + 1u;
    TF_R(17) TF_R(29) TF_R(16) TF_R(24)
    x0 += ks2; x1 += k0 + 2u;
    TF_R(13) TF_R(15) TF_R(26) TF_R(6)
    x0 += k0; x1 += k1 + 3u;
    TF_R(17) TF_R(29) TF_R(16) TF_R(24)
    x0 += k1; x1 += ks2 + 4u;
    TF_R(13) TF_R(15) TF_R(26) TF_R(6)
    x0 += ks2; x1 += k0 + 5u;
#undef TF_R
    o0 = x0; o1 = x1;
}

__device__ inline int expert_of(int r, const int* bases) {
    int e = 0;
    #pragma unroll
    for (int i = 1; i < N_EXP; ++i) if (r >= bases[i]) e = i;
    return e;
}

// ---------------- policy + routing ----------------

__global__ __launch_bounds__(256) void policy_k(
    const float* __restrict__ x, const float* __restrict__ pw1,
    const float* __restrict__ pb1, const float* __restrict__ pg1,
    const float* __restrict__ pbb1, const float* __restrict__ pw2,
    const float* __restrict__ pb2, int2* __restrict__ top2, int* __restrict__ counts)
{
    const int t = blockIdx.x;
    const int lid = threadIdx.x;
    __shared__ float xs[512];
    __shared__ float hb[256];
    __shared__ float red[4];
    __shared__ float sc[8];

    xs[lid]       = x[(long long)t * 512 + lid];
    xs[lid + 256] = x[(long long)t * 512 + 256 + lid];
    __syncthreads();

    float acc = pb1[lid];
    for (int d = 0; d < 512; ++d)
        acc = fmaf(xs[d], pw1[d * 256 + lid], acc);

    float s  = block_sum256(acc, red);
    float sq = block_sum256(acc * acc, red);
    float mean = s * (1.0f / 256.0f);
    float var  = sq * (1.0f / 256.0f) - mean * mean;
    float rstd = rsqrtf(var + 1e-5f);
    float hn = (acc - mean) * rstd * pg1[lid] + pbb1[lid];
    hb[lid] = gelu_f(hn);
    __syncthreads();

    if (lid < 8) {
        float lg = pb2[lid];
        for (int j = 0; j < 256; ++j)
            lg = fmaf(hb[j], pw2[j * 8 + lid], lg);
        // jax_threefry_partitionable path: bits = o0 ^ o1 of tf(key, 0, i)
        unsigned idx = (unsigned)t * 8u + (unsigned)lid;
        unsigned o0, o1;
        threefry2x32(0u, 42u, 0u, idx, o0, o1);
        unsigned bits = o0 ^ o1;
        float u = __uint_as_float((bits >> 9) | 0x3f800000u) - 1.0f;
        float gml = -logf(-logf(u + 1e-10f) + 1e-10f);
        sc[lid] = lg + gml;   // TEMP = 1
    }
    __syncthreads();
    if (lid == 0) {
        float b0 = -INFINITY; int i0 = 0;
        #pragma unroll
        for (int e = 0; e < 8; ++e) if (sc[e] > b0) { b0 = sc[e]; i0 = e; }
        float b1v = -INFINITY; int i1 = 0;
        #pragma unroll
        for (int e = 0; e < 8; ++e) if (e != i0 && sc[e] > b1v) { b1v = sc[e]; i1 = e; }
        top2[t] = make_int2(i0, i1);
        atomicAdd(&counts[i0], 1);
        atomicAdd(&counts[i1], 1);
    }
}

__global__ void prefix_k(const int* __restrict__ counts, int* __restrict__ cursor,
                         int* __restrict__ bases) {
    if (threadIdx.x == 0 && blockIdx.x == 0) {
        int s = 0;
        for (int e = 0; e < N_EXP; ++e) { bases[e] = s; cursor[e] = s; s += counts[e]; }
    }
}

__global__ __launch_bounds__(256) void scatter_k(const int2* __restrict__ top2,
                                                 int* __restrict__ cursor,
                                                 int* __restrict__ list) {
    int t = blockIdx.x * 256 + threadIdx.x;
    int2 p = top2[t];
    int pos = atomicAdd(&cursor[p.x], 1); list[pos] = t;
    pos     = atomicAdd(&cursor[p.y], 1); list[pos] = t;
}

// ---------------- x -> bf16 cast ----------------

__global__ __launch_bounds__(256) void cast_x_k(const float* __restrict__ x,
                                                bf16* __restrict__ xb) {
    int i = (blockIdx.x * 256 + threadIdx.x) * 4;
    float4 v = *(const float4*)(x + i);
    bf16 o[4] = { (bf16)v.x, (bf16)v.y, (bf16)v.z, (bf16)v.w };
    *(unsigned long long*)(xb + i) = *(unsigned long long*)o;
}

// ---------------- MFMA grouped GEMM ----------------
// C[rbase+m][n] = act(A[row][k] * W_e[k][n] + bias_e[n]); A bf16, W fp32->bf16 staged.
// gather: A row = list[rbase+m] (token), else rbase+m. Cmir: optional bf16 mirror.

template <typename CT>
__global__ __launch_bounds__(256) void mgemm_k(
    const bf16* __restrict__ A, const int* __restrict__ gather,
    const float* __restrict__ W, long long westride,
    const float* __restrict__ bias, int bestride,
    CT* __restrict__ C, bf16* __restrict__ Cmir,
    const int* __restrict__ counts, const int* __restrict__ bases,
    int K, int N, int act)
{
    const int e   = blockIdx.z;
    const int cnt = counts[e];
    const int m0  = blockIdx.y * TM;
    if (m0 >= cnt) return;
    const int rbase = bases[e];
    const int n0  = blockIdx.x * TN;
    const float* We = W + (long long)e * westride;

    __shared__ unsigned short As[TM * LDAB];  // [m][k], bf16 bits
    __shared__ unsigned short Bs[TN * LDAB];  // [n][k], bf16 bits

    const int tid  = threadIdx.x;
    const int lane = tid & 63;
    const int wv   = tid >> 6;
    const int wm   = (wv & 1) * 64;
    const int wn   = (wv >> 1) * 64;
    const int q    = lane >> 4;
    const int ln   = lane & 15;

    // A staging coords: thread loads 8 bf16 (16B) for two rows
    const int ar = tid >> 2;
    const int ak = (tid & 3) * 8;
    long long arow0, arow1;
    {
        int r0 = m0 + ar;      if (r0 > cnt - 1) r0 = cnt - 1;
        int r1 = m0 + 64 + ar; if (r1 > cnt - 1) r1 = cnt - 1;
        long long p0 = gather ? (long long)gather[rbase + r0] : (long long)(rbase + r0);
        long long p1 = gather ? (long long)gather[rbase + r1] : (long long)(rbase + r1);
        arow0 = p0 * K; arow1 = p1 * K;
    }
    // B staging coords: thread loads float4 along N for 4 k values
    const int bn = (tid & 31) * 4;
    const int bk = tid >> 5;

    floatx4 acc[4][4];
    #pragma unroll
    for (int i = 0; i < 4; ++i)
        #pragma unroll
        for (int j = 0; j < 4; ++j)
            acc[i][j] = (floatx4){0.f, 0.f, 0.f, 0.f};

    for (int k0 = 0; k0 < K; k0 += TK) {
        uint4 va0 = *(const uint4*)(A + arow0 + k0 + ak);
        uint4 va1 = *(const uint4*)(A + arow1 + k0 + ak);
        *(uint4*)(&As[ar * LDAB + ak])        = va0;
        *(uint4*)(&As[(64 + ar) * LDAB + ak]) = va1;
        #pragma unroll
        for (int p = 0; p < 4; ++p) {
            int k = bk + 8 * p;
            float4 w = *(const float4*)(We + (long long)(k0 + k) * N + n0 + bn);
            bf16 w0 = (bf16)w.x, w1 = (bf16)w.y, w2 = (bf16)w.z, w3 = (bf16)w.w;
            Bs[(bn + 0) * LDAB + k] = *(unsigned short*)&w0;
            Bs[(bn + 1) * LDAB + k] = *(unsigned short*)&w1;
            Bs[(bn + 2) * LDAB + k] = *(unsigned short*)&w2;
            Bs[(bn + 3) * LDAB + k] = *(unsigned short*)&w3;
        }
        __syncthreads();

        short8 a_frag[4], b_frag[4];
        #pragma unroll
        for (int i = 0; i < 4; ++i)
            a_frag[i] = *(const short8*)(&As[(wm + i * 16 + ln) * LDAB + q * 8]);
        #pragma unroll
        for (int j = 0; j < 4; ++j)
            b_frag[j] = *(const short8*)(&Bs[(wn + j * 16 + ln) * LDAB + q * 8]);
        #pragma unroll
        for (int i = 0; i < 4; ++i)
            #pragma unroll
            for (int j = 0; j < 4; ++j)
                acc[i][j] = __builtin_amdgcn_mfma_f32_16x16x32_bf16(
                    a_frag[i], b_frag[j], acc[i][j], 0, 0, 0);
        __syncthreads();
    }

    // epilogue: C/D layout col = lane&15, row = quad*4 + reg
    #pragma unroll
    for (int i = 0; i < 4; ++i) {
        int rbase_i = m0 + wm + i * 16 + q * 4;
        #pragma unroll
        for (int j = 0; j < 4; ++j) {
            int n = n0 + wn + j * 16 + ln;
            float bv = bias[e * bestride + n];
            #pragma unroll
            for (int rg = 0; rg < 4; ++rg) {
                int r = rbase_i + rg;
                if (r >= cnt) continue;
                float v = acc[i][j][rg] + bv;
                if (act) v = gelu_f(v);
                long long off = (long long)(rbase + r) * N + n;
                C[off] = (CT)v;
                if (Cmir) Cmir[off] = (bf16)v;
            }
        }
    }
}

// ---------------- LN + gate + residual (row-global), writes h fp32 + hb bf16 ----------------

__global__ __launch_bounds__(256) void lngate_k(
    float* __restrict__ h, bf16* __restrict__ hb, const float* __restrict__ h2,
    const float* __restrict__ ng, const float* __restrict__ nb,
    const float* __restrict__ gw, const int* __restrict__ bases, int l)
{
    const int r = blockIdx.x;
    const int e = expert_of(r, bases);
    const int lid = threadIdx.x;
    const float* hr  = h  + (long long)r * 1024;
    const float* h2r = h2 + (long long)r * 1024;
    const int off = (e * 2 + l) * 1024;
    __shared__ float red[4];

    float s = 0.f, sq = 0.f, dt = 0.f;
    float hv[4], h2v[4];
    #pragma unroll
    for (int i = 0; i < 4; ++i) {
        int j = lid + 256 * i;
        float a = h2r[j];
        float b = hr[j];
        hv[i] = b; h2v[i] = a;
        s += a; sq += a * a;
        dt = fmaf(b, gw[off + j], dt);
    }
    s  = block_sum256(s, red);
    sq = block_sum256(sq, red);
    dt = block_sum256(dt, red);
    float mean = s * (1.f / 1024.f);
    float rstd = rsqrtf(sq * (1.f / 1024.f) - mean * mean + 1e-5f);
    float gate = 1.f / (1.f + expf(-dt));
    float* hw  = h  + (long long)r * 1024;
    bf16*  hbw = hb + (long long)r * 1024;
    #pragma unroll
    for (int i = 0; i < 4; ++i) {
        int j = lid + 256 * i;
        float v = (h2v[i] - mean) * rstd * ng[off + j] + nb[off + j];
        float nh = hv[i] + gate * v;
        hw[j] = nh;
        hbw[j] = (bf16)nh;
    }
}

// ---------------- final LN(x + out) + combine ----------------

__global__ __launch_bounds__(256) void final_k(
    const float* __restrict__ x, const bf16* __restrict__ orow,
    const float* __restrict__ fng, const float* __restrict__ fnb,
    const int* __restrict__ bases, const int* __restrict__ list,
    float* __restrict__ out)
{
    const int r = blockIdx.x;
    const int e = expert_of(r, bases);
    const int t = list[r];
    const int lid = threadIdx.x;
    __shared__ float red[4];

    float y[2];
    float s = 0.f, sq = 0.f;
    #pragma unroll
    for (int i = 0; i < 2; ++i) {
        int j = lid + 256 * i;
        float v = x[(long long)t * 512 + j] + (float)orow[(long long)r * 512 + j];
        y[i] = v; s += v; sq += v * v;
    }
    s  = block_sum256(s, red);
    sq = block_sum256(sq, red);
    float mean = s * (1.f / 512.f);
    float rstd = rsqrtf(sq * (1.f / 512.f) - mean * mean + 1e-5f);
    #pragma unroll
    for (int i = 0; i < 2; ++i) {
        int j = lid + 256 * i;
        float v = (y[i] - mean) * rstd * fng[e * 512 + j] + fnb[e * 512 + j];
        atomicAdd(&out[(long long)t * 512 + j], v);
    }
}

// ---------------- launch ----------------

extern "C" void kernel_launch(void* const* d_in, const int* in_sizes, int n_in,
                              void* d_out, int out_size, void* d_ws, size_t ws_size,
                              hipStream_t stream) {
    const float* x    = (const float*)d_in[0];
    const float* pw1  = (const float*)d_in[1];
    const float* pb1  = (const float*)d_in[2];
    const float* pg1  = (const float*)d_in[3];
    const float* pbb1 = (const float*)d_in[4];
    const float* pw2  = (const float*)d_in[5];
    const float* pb2  = (const float*)d_in[6];
    const float* Win  = (const float*)d_in[7];
    const float* b_in = (const float*)d_in[8];
    const float* W1   = (const float*)d_in[9];
    const float* b1   = (const float*)d_in[10];
    const float* W2   = (const float*)d_in[11];
    const float* b2   = (const float*)d_in[12];
    const float* ng   = (const float*)d_in[13];
    const float* nb   = (const float*)d_in[14];
    const float* gw   = (const float*)d_in[15];
    const float* Wout = (const float*)d_in[16];
    const float* bout = (const float*)d_in[17];
    const float* fng  = (const float*)d_in[18];
    const float* fnb  = (const float*)d_in[19];
    float* out = (float*)d_out;
    (void)ws_size; (void)in_sizes; (void)n_in;

    char* ws = (char*)d_ws;
    int* counts = (int*)ws;        // 8 ints @ 0
    int* cursor = counts + 8;      // 8 ints @ 32
    int* bases  = cursor + 8;      // 8 ints @ 64
    int2* top2  = (int2*)(ws + 128);             // 16 KB
    int*  list  = (int*)(ws + 128 + 2048 * 8);   // 16 KB
    size_t o = 128 + 2048 * 8 + 4096 * 4;
    o = (o + 255) & ~(size_t)255;
    bf16*  xb   = (bf16*) (ws + o); o += (size_t)NTOK * 512 * 2;      //  2 MB
    float* h    = (float*)(ws + o); o += (size_t)TOTROWS * 1024 * 4;  // 16 MB
    bf16*  hb   = (bf16*) (ws + o); o += (size_t)TOTROWS * 1024 * 2;  //  8 MB
    bf16*  tb   = (bf16*) (ws + o); o += (size_t)TOTROWS * 2048 * 2;  // 16 MB
    float* h2   = (float*)(ws + o); o += (size_t)TOTROWS * 1024 * 4;  // 16 MB
    bf16*  orow = (bf16*) (ws + o); o += (size_t)TOTROWS * 512 * 2;   //  4 MB
    // total ~62 MB

    hipMemsetAsync(d_out, 0, (size_t)out_size * sizeof(float), stream);
    hipMemsetAsync(ws, 0, 64, stream);  // counts + cursor

    policy_k<<<NTOK, 256, 0, stream>>>(x, pw1, pb1, pg1, pbb1, pw2, pb2, top2, counts);
    prefix_k<<<1, 64, 0, stream>>>(counts, cursor, bases);
    scatter_k<<<NTOK / 256, 256, 0, stream>>>(top2, cursor, list);
    cast_x_k<<<NTOK * 512 / 1024, 256, 0, stream>>>(x, xb);

    // h (+hb) = gather(x) @ Win_e + b_in    [4096,512]x[512,1024]
    mgemm_k<float><<<dim3(8, 16, 8), 256, 0, stream>>>(
        xb, list, Win, (long long)512 * 1024, b_in, 1024, h, hb,
        counts, bases, 512, 1024, 0);

    for (int l = 0; l < 2; ++l) {
        // tb = gelu(hb @ W1_el + b1)        [4096,1024]x[1024,2048]
        mgemm_k<bf16><<<dim3(16, 16, 8), 256, 0, stream>>>(
            hb, nullptr, W1 + (long long)l * 1024 * 2048, (long long)2 * 1024 * 2048,
            b1 + l * 2048, 2 * 2048, tb, (bf16*)nullptr,
            counts, bases, 1024, 2048, 1);
        // h2 = tb @ W2_el + b2              [4096,2048]x[2048,1024]
        mgemm_k<float><<<dim3(8, 16, 8), 256, 0, stream>>>(
            tb, nullptr, W2 + (long long)l * 2048 * 1024, (long long)2 * 2048 * 1024,
            b2 + l * 1024, 2 * 1024, h2, (bf16*)nullptr,
            counts, bases, 2048, 1024, 0);
        // h += sigmoid(h . gw) * LN(h2); hb mirror
        lngate_k<<<TOTROWS, 256, 0, stream>>>(h, hb, h2, ng, nb, gw, bases, l);
    }

    // orow = hb @ Wout_e + bout             [4096,1024]x[1024,512]
    mgemm_k<bf16><<<dim3(4, 16, 8), 256, 0, stream>>>(
        hb, nullptr, Wout, (long long)1024 * 512, bout, 512, orow, (bf16*)nullptr,
        counts, bases, 1024, 512, 0);

    // out[t] += LN(x[t] + orow)
    final_k<<<TOTROWS, 256, 0, stream>>>(x, orow, fng, fnb, bases, list, out);
}

// Round 5
// 828.311 us; speedup vs baseline: 3.7003x; 1.5327x over previous
//
#include <hip/hip_runtime.h>
#include <hip/hip_bf16.h>

#define N_EXP   8
#define NTOK    2048   // B*S
#define TOTROWS 4096   // NTOK * TOP_K

typedef __hip_bfloat16 bf16;
typedef __attribute__((ext_vector_type(8))) short short8;   // 8 bf16 (4 VGPRs)
typedef __attribute__((ext_vector_type(4))) float floatx4;  // MFMA acc

#define TM 128
#define TN 128
#define TK 32
#define LDAB 40   // padded bf16 row stride for LDS tiles (80B: 16B-aligned, 2-way max)

// ---------------- helpers ----------------

__device__ inline float gelu_f(float v) {
    return 0.5f * v * (1.0f + erff(v * 0.70710678118654752440f));
}

__device__ inline float block_sum256(float v, float* red) {
    #pragma unroll
    for (int off = 32; off > 0; off >>= 1)
        v += __shfl_down(v, off, 64);
    __syncthreads();
    if ((threadIdx.x & 63) == 0) red[threadIdx.x >> 6] = v;
    __syncthreads();
    return red[0] + red[1] + red[2] + red[3];
}

__device__ inline unsigned rotl32(unsigned v, int d) { return (v << d) | (v >> (32 - d)); }

// JAX threefry2x32, key = (k0,k1)
__device__ inline void threefry2x32(unsigned k0, unsigned k1, unsigned x0, unsigned x1,
                                    unsigned& o0, unsigned& o1) {
    unsigned ks2 = k0 ^ k1 ^ 0x1BD11BDAu;
    x0 += k0; x1 += k1;
#define TF_R(r) { x0 += x1; x1 = rotl32(x1, r); x1 ^= x0; }
    TF_R(13) TF_R(15) TF_R(26) TF_R(6)
    x0 += k1; x1 += ks2 + 1u;
    TF_R(17) TF_R(29) TF_R(16) TF_R(24)
    x0 += ks2; x1 += k0 + 2u;
    TF_R(13) TF_R(15) TF_R(26) TF_R(6)
    x0 += k0; x1 += k1 + 3u;
    TF_R(17) TF_R(29) TF_R(16) TF_R(24)
    x0 += k1; x1 += ks2 + 4u;
    TF_R(13) TF_R(15) TF_R(26) TF_R(6)
    x0 += ks2; x1 += k0 + 5u;
#undef TF_R
    o0 = x0; o1 = x1;
}

__device__ inline int expert_of(int r, const int* bases) {
    int e = 0;
    #pragma unroll
    for (int i = 1; i < N_EXP; ++i) if (r >= bases[i]) e = i;
    return e;
}

// ---------------- policy + routing ----------------

__global__ __launch_bounds__(256) void policy_k(
    const float* __restrict__ x, const float* __restrict__ pw1,
    const float* __restrict__ pb1, const float* __restrict__ pg1,
    const float* __restrict__ pbb1, const float* __restrict__ pw2,
    const float* __restrict__ pb2, int2* __restrict__ top2, int* __restrict__ counts)
{
    const int t = blockIdx.x;
    const int lid = threadIdx.x;
    __shared__ float xs[512];
    __shared__ float hb[256];
    __shared__ float red[4];
    __shared__ float sc[8];

    xs[lid]       = x[(long long)t * 512 + lid];
    xs[lid + 256] = x[(long long)t * 512 + 256 + lid];
    __syncthreads();

    float acc = pb1[lid];
    for (int d = 0; d < 512; ++d)
        acc = fmaf(xs[d], pw1[d * 256 + lid], acc);

    float s  = block_sum256(acc, red);
    float sq = block_sum256(acc * acc, red);
    float mean = s * (1.0f / 256.0f);
    float var  = sq * (1.0f / 256.0f) - mean * mean;
    float rstd = rsqrtf(var + 1e-5f);
    float hn = (acc - mean) * rstd * pg1[lid] + pbb1[lid];
    hb[lid] = gelu_f(hn);
    __syncthreads();

    if (lid < 8) {
        float lg = pb2[lid];
        for (int j = 0; j < 256; ++j)
            lg = fmaf(hb[j], pw2[j * 8 + lid], lg);
        // jax_threefry_partitionable path: bits = o0 ^ o1 of tf(key, 0, i)
        unsigned idx = (unsigned)t * 8u + (unsigned)lid;
        unsigned o0, o1;
        threefry2x32(0u, 42u, 0u, idx, o0, o1);
        unsigned bits = o0 ^ o1;
        float u = __uint_as_float((bits >> 9) | 0x3f800000u) - 1.0f;
        float gml = -logf(-logf(u + 1e-10f) + 1e-10f);
        sc[lid] = lg + gml;   // TEMP = 1
    }
    __syncthreads();
    if (lid == 0) {
        float b0 = -INFINITY; int i0 = 0;
        #pragma unroll
        for (int e = 0; e < 8; ++e) if (sc[e] > b0) { b0 = sc[e]; i0 = e; }
        float b1v = -INFINITY; int i1 = 0;
        #pragma unroll
        for (int e = 0; e < 8; ++e) if (e != i0 && sc[e] > b1v) { b1v = sc[e]; i1 = e; }
        top2[t] = make_int2(i0, i1);
        atomicAdd(&counts[i0], 1);
        atomicAdd(&counts[i1], 1);
    }
}

__global__ void prefix_k(const int* __restrict__ counts, int* __restrict__ cursor,
                         int* __restrict__ bases) {
    if (threadIdx.x == 0 && blockIdx.x == 0) {
        int s = 0;
        for (int e = 0; e < N_EXP; ++e) { bases[e] = s; cursor[e] = s; s += counts[e]; }
    }
}

__global__ __launch_bounds__(256) void scatter_k(const int2* __restrict__ top2,
                                                 int* __restrict__ cursor,
                                                 int* __restrict__ list) {
    int t = blockIdx.x * 256 + threadIdx.x;
    int2 p = top2[t];
    int pos = atomicAdd(&cursor[p.x], 1); list[pos] = t;
    pos     = atomicAdd(&cursor[p.y], 1); list[pos] = t;
}

// ---------------- x -> bf16 cast ----------------

__global__ __launch_bounds__(256) void cast_x_k(const float* __restrict__ x,
                                                bf16* __restrict__ xb) {
    int i = (blockIdx.x * 256 + threadIdx.x) * 4;
    float4 v = *(const float4*)(x + i);
    bf16 o[4] = { (bf16)v.x, (bf16)v.y, (bf16)v.z, (bf16)v.w };
    *(unsigned long long*)(xb + i) = *(unsigned long long*)o;
}

// ---------------- MFMA grouped GEMM ----------------
// C[rbase+m][n] = act(A[row][k] * W_e[k][n] + bias_e[n]); A bf16, W fp32->bf16
// staged with in-register transpose (lane-per-n, vector ds_write_b128).
// gather: A row = list[rbase+m] (token), else rbase+m. Cmir: optional bf16 mirror.

template <typename CT>
__global__ __launch_bounds__(256) void mgemm_k(
    const bf16* __restrict__ A, const int* __restrict__ gather,
    const float* __restrict__ W, long long westride,
    const float* __restrict__ bias, int bestride,
    CT* __restrict__ C, bf16* __restrict__ Cmir,
    const int* __restrict__ counts, const int* __restrict__ bases,
    int K, int N, int act)
{
    const int e   = blockIdx.z;
    const int cnt = counts[e];
    const int m0  = blockIdx.y * TM;
    if (m0 >= cnt) return;
    const int rbase = bases[e];
    const int n0  = blockIdx.x * TN;
    const float* We = W + (long long)e * westride;

    __shared__ unsigned short As[TM * LDAB];  // [m][k], bf16 bits
    __shared__ unsigned short Bs[TN * LDAB];  // [n][k], bf16 bits

    const int tid  = threadIdx.x;
    const int lane = tid & 63;
    const int wv   = tid >> 6;
    const int wm   = (wv & 1) * 64;
    const int wn   = (wv >> 1) * 64;
    const int q    = lane >> 4;
    const int ln   = lane & 15;

    // A staging coords: thread loads 8 bf16 (16B) for two rows
    const int ar = tid >> 2;
    const int ak = (tid & 3) * 8;
    long long arow0, arow1;
    {
        int r0 = m0 + ar;      if (r0 > cnt - 1) r0 = cnt - 1;
        int r1 = m0 + 64 + ar; if (r1 > cnt - 1) r1 = cnt - 1;
        long long p0 = gather ? (long long)gather[rbase + r0] : (long long)(rbase + r0);
        long long p1 = gather ? (long long)gather[rbase + r1] : (long long)(rbase + r1);
        arow0 = p0 * K; arow1 = p1 * K;
    }
    // B staging coords: thread owns one n column, 16 consecutive k values.
    // Lane-consecutive n -> 256B coalesced global reads; transpose in registers;
    // two ds_write_b128 at Bs[n][kb..kb+16] (2-way bank aliasing only).
    const int bn = (wv & 1) * 64 + lane;   // n within tile, 0..127
    const int bkb = (wv >> 1) * 16;        // k sub-base: 0 or 16

    floatx4 acc[4][4];
    #pragma unroll
    for (int i = 0; i < 4; ++i)
        #pragma unroll
        for (int j = 0; j < 4; ++j)
            acc[i][j] = (floatx4){0.f, 0.f, 0.f, 0.f};

    for (int k0 = 0; k0 < K; k0 += TK) {
        uint4 va0 = *(const uint4*)(A + arow0 + k0 + ak);
        uint4 va1 = *(const uint4*)(A + arow1 + k0 + ak);

        float wf[16];
        #pragma unroll
        for (int kk = 0; kk < 16; ++kk)
            wf[kk] = We[(long long)(k0 + bkb + kk) * N + n0 + bn];

        *(uint4*)(&As[ar * LDAB + ak])        = va0;
        *(uint4*)(&As[(64 + ar) * LDAB + ak]) = va1;

        union { unsigned short us[8]; uint4 v; } p0, p1;
        #pragma unroll
        for (int kk = 0; kk < 8; ++kk) {
            bf16 b0 = (bf16)wf[kk];
            bf16 b1 = (bf16)wf[kk + 8];
            p0.us[kk] = *(unsigned short*)&b0;
            p1.us[kk] = *(unsigned short*)&b1;
        }
        *(uint4*)(&Bs[bn * LDAB + bkb])     = p0.v;
        *(uint4*)(&Bs[bn * LDAB + bkb + 8]) = p1.v;
        __syncthreads();

        short8 a_frag[4], b_frag[4];
        #pragma unroll
        for (int i = 0; i < 4; ++i)
            a_frag[i] = *(const short8*)(&As[(wm + i * 16 + ln) * LDAB + q * 8]);
        #pragma unroll
        for (int j = 0; j < 4; ++j)
            b_frag[j] = *(const short8*)(&Bs[(wn + j * 16 + ln) * LDAB + q * 8]);
        #pragma unroll
        for (int i = 0; i < 4; ++i)
            #pragma unroll
            for (int j = 0; j < 4; ++j)
                acc[i][j] = __builtin_amdgcn_mfma_f32_16x16x32_bf16(
                    a_frag[i], b_frag[j], acc[i][j], 0, 0, 0);
        __syncthreads();
    }

    // epilogue: C/D layout col = lane&15, row = quad*4 + reg
    #pragma unroll
    for (int i = 0; i < 4; ++i) {
        int rbase_i = m0 + wm + i * 16 + q * 4;
        #pragma unroll
        for (int j = 0; j < 4; ++j) {
            int n = n0 + wn + j * 16 + ln;
            float bv = bias[e * bestride + n];
            #pragma unroll
            for (int rg = 0; rg < 4; ++rg) {
                int r = rbase_i + rg;
                if (r >= cnt) continue;
                float v = acc[i][j][rg] + bv;
                if (act) v = gelu_f(v);
                long long off = (long long)(rbase + r) * N + n;
                C[off] = (CT)v;
                if (Cmir) Cmir[off] = (bf16)v;
            }
        }
    }
}

// ---------------- LN + gate + residual (row-global), writes h fp32 + hb bf16 ----------------

__global__ __launch_bounds__(256) void lngate_k(
    float* __restrict__ h, bf16* __restrict__ hb, const float* __restrict__ h2,
    const float* __restrict__ ng, const float* __restrict__ nb,
    const float* __restrict__ gw, const int* __restrict__ bases, int l)
{
    const int r = blockIdx.x;
    const int e = expert_of(r, bases);
    const int lid = threadIdx.x;
    const float* hr  = h  + (long long)r * 1024;
    const float* h2r = h2 + (long long)r * 1024;
    const int off = (e * 2 + l) * 1024;
    __shared__ float red[4];

    float s = 0.f, sq = 0.f, dt = 0.f;
    float hv[4], h2v[4];
    #pragma unroll
    for (int i = 0; i < 4; ++i) {
        int j = lid + 256 * i;
        float a = h2r[j];
        float b = hr[j];
        hv[i] = b; h2v[i] = a;
        s += a; sq += a * a;
        dt = fmaf(b, gw[off + j], dt);
    }
    s  = block_sum256(s, red);
    sq = block_sum256(sq, red);
    dt = block_sum256(dt, red);
    float mean = s * (1.f / 1024.f);
    float rstd = rsqrtf(sq * (1.f / 1024.f) - mean * mean + 1e-5f);
    float gate = 1.f / (1.f + expf(-dt));
    float* hw  = h  + (long long)r * 1024;
    bf16*  hbw = hb + (long long)r * 1024;
    #pragma unroll
    for (int i = 0; i < 4; ++i) {
        int j = lid + 256 * i;
        float v = (h2v[i] - mean) * rstd * ng[off + j] + nb[off + j];
        float nh = hv[i] + gate * v;
        hw[j] = nh;
        hbw[j] = (bf16)nh;
    }
}

// ---------------- final LN(x + out) + combine ----------------

__global__ __launch_bounds__(256) void final_k(
    const float* __restrict__ x, const bf16* __restrict__ orow,
    const float* __restrict__ fng, const float* __restrict__ fnb,
    const int* __restrict__ bases, const int* __restrict__ list,
    float* __restrict__ out)
{
    const int r = blockIdx.x;
    const int e = expert_of(r, bases);
    const int t = list[r];
    const int lid = threadIdx.x;
    __shared__ float red[4];

    float y[2];
    float s = 0.f, sq = 0.f;
    #pragma unroll
    for (int i = 0; i < 2; ++i) {
        int j = lid + 256 * i;
        float v = x[(long long)t * 512 + j] + (float)orow[(long long)r * 512 + j];
        y[i] = v; s += v; sq += v * v;
    }
    s  = block_sum256(s, red);
    sq = block_sum256(sq, red);
    float mean = s * (1.f / 512.f);
    float rstd = rsqrtf(sq * (1.f / 512.f) - mean * mean + 1e-5f);
    #pragma unroll
    for (int i = 0; i < 2; ++i) {
        int j = lid + 256 * i;
        float v = (y[i] - mean) * rstd * fng[e * 512 + j] + fnb[e * 512 + j];
        atomicAdd(&out[(long long)t * 512 + j], v);
    }
}

// ---------------- launch ----------------

extern "C" void kernel_launch(void* const* d_in, const int* in_sizes, int n_in,
                              void* d_out, int out_size, void* d_ws, size_t ws_size,
                              hipStream_t stream) {
    const float* x    = (const float*)d_in[0];
    const float* pw1  = (const float*)d_in[1];
    const float* pb1  = (const float*)d_in[2];
    const float* pg1  = (const float*)d_in[3];
    const float* pbb1 = (const float*)d_in[4];
    const float* pw2  = (const float*)d_in[5];
    const float* pb2  = (const float*)d_in[6];
    const float* Win  = (const float*)d_in[7];
    const float* b_in = (const float*)d_in[8];
    const float* W1   = (const float*)d_in[9];
    const float* b1   = (const float*)d_in[10];
    const float* W2   = (const float*)d_in[11];
    const float* b2   = (const float*)d_in[12];
    const float* ng   = (const float*)d_in[13];
    const float* nb   = (const float*)d_in[14];
    const float* gw   = (const float*)d_in[15];
    const float* Wout = (const float*)d_in[16];
    const float* bout = (const float*)d_in[17];
    const float* fng  = (const float*)d_in[18];
    const float* fnb  = (const float*)d_in[19];
    float* out = (float*)d_out;
    (void)ws_size; (void)in_sizes; (void)n_in;

    char* ws = (char*)d_ws;
    int* counts = (int*)ws;        // 8 ints @ 0
    int* cursor = counts + 8;      // 8 ints @ 32
    int* bases  = cursor + 8;      // 8 ints @ 64
    int2* top2  = (int2*)(ws + 128);             // 16 KB
    int*  list  = (int*)(ws + 128 + 2048 * 8);   // 16 KB
    size_t o = 128 + 2048 * 8 + 4096 * 4;
    o = (o + 255) & ~(size_t)255;
    bf16*  xb   = (bf16*) (ws + o); o += (size_t)NTOK * 512 * 2;      //  2 MB
    float* h    = (float*)(ws + o); o += (size_t)TOTROWS * 1024 * 4;  // 16 MB
    bf16*  hb   = (bf16*) (ws + o); o += (size_t)TOTROWS * 1024 * 2;  //  8 MB
    bf16*  tb   = (bf16*) (ws + o); o += (size_t)TOTROWS * 2048 * 2;  // 16 MB
    float* h2   = (float*)(ws + o); o += (size_t)TOTROWS * 1024 * 4;  // 16 MB
    bf16*  orow = (bf16*) (ws + o); o += (size_t)TOTROWS * 512 * 2;   //  4 MB
    // total ~62 MB

    hipMemsetAsync(d_out, 0, (size_t)out_size * sizeof(float), stream);
    hipMemsetAsync(ws, 0, 64, stream);  // counts + cursor

    policy_k<<<NTOK, 256, 0, stream>>>(x, pw1, pb1, pg1, pbb1, pw2, pb2, top2, counts);
    prefix_k<<<1, 64, 0, stream>>>(counts, cursor, bases);
    scatter_k<<<NTOK / 256, 256, 0, stream>>>(top2, cursor, list);
    cast_x_k<<<NTOK * 512 / 1024, 256, 0, stream>>>(x, xb);

    // h (+hb) = gather(x) @ Win_e + b_in    [4096,512]x[512,1024]
    mgemm_k<float><<<dim3(8, 16, 8), 256, 0, stream>>>(
        xb, list, Win, (long long)512 * 1024, b_in, 1024, h, hb,
        counts, bases, 512, 1024, 0);

    for (int l = 0; l < 2; ++l) {
        // tb = gelu(hb @ W1_el + b1)        [4096,1024]x[1024,2048]
        mgemm_k<bf16><<<dim3(16, 16, 8), 256, 0, stream>>>(
            hb, nullptr, W1 + (long long)l * 1024 * 2048, (long long)2 * 1024 * 2048,
            b1 + l * 2048, 2 * 2048, tb, (bf16*)nullptr,
            counts, bases, 1024, 2048, 1);
        // h2 = tb @ W2_el + b2              [4096,2048]x[2048,1024]
        mgemm_k<float><<<dim3(8, 16, 8), 256, 0, stream>>>(
            tb, nullptr, W2 + (long long)l * 2048 * 1024, (long long)2 * 2048 * 1024,
            b2 + l * 1024, 2 * 1024, h2, (bf16*)nullptr,
            counts, bases, 2048, 1024, 0);
        // h += sigmoid(h . gw) * LN(h2); hb mirror
        lngate_k<<<TOTROWS, 256, 0, stream>>>(h, hb, h2, ng, nb, gw, bases, l);
    }

    // orow = hb @ Wout_e + bout             [4096,1024]x[1024,512]
    mgemm_k<bf16><<<dim3(4, 16, 8), 256, 0, stream>>>(
        hb, nullptr, Wout, (long long)1024 * 512, bout, 512, orow, (bf16*)nullptr,
        counts, bases, 1024, 512, 0);

    // out[t] += LN(x[t] + orow)
    final_k<<<TOTROWS, 256, 0, stream>>>(x, orow, fng, fnb, bases, list, out);
}